// Round 7
// baseline (386.259 us; speedup 1.0000x reference)
//
#include <hip/hip_runtime.h>
#include <hip/hip_fp16.h>
#include <math.h>

#define NBINS   4096
#define GB_HIST 128
#define GBC     128     // count/scatter grid blocks
#define CAP     2048
#define DCH     64
#define NBMAX   1024    // max buckets (N <= 65536)
#define SCAN_CH 2048

struct Ctrl {
    double thr;
    int cand_cnt;
    int b0, b1;
    int base0;
    float s0, s1;
};

__device__ __forceinline__ int bin_of(float v) {
    int b = (int)(v * (float)NBINS);
    if (b < 0) b = 0;
    if (b >= NBINS) b = NBINS - 1;
    return b;
}

// ---------- LDS histogram, dense (non-atomic) flush ----------
__global__ void k_hist(const float* __restrict__ att, int E, int* __restrict__ hist2d) {
    __shared__ int lh[NBINS];   // 16 KB
    int t = threadIdx.x;
    for (int b = t; b < NBINS; b += 256) lh[b] = 0;
    __syncthreads();
    for (int i = blockIdx.x * 256 + t; i < E; i += GB_HIST * 256)
        atomicAdd(&lh[bin_of(att[i])], 1);
    __syncthreads();
    for (int b = t; b < NBINS; b += 256)
        hist2d[blockIdx.x * NBINS + b] = lh[b];
}

// 16 blocks x 256: fold 128 partial hists, emit per-256-bin-chunk sums
__global__ void k_fold(const int* __restrict__ hist2d, int* __restrict__ hist,
                       int* __restrict__ csum) {
    __shared__ int sh[4];
    int t = threadIdx.x;
    int j = blockIdx.x * 256 + t;
    int s = 0;
    for (int k = 0; k < GB_HIST; k++) s += hist2d[k * NBINS + j];
    hist[j] = s;
    int r = s;
    for (int off = 32; off > 0; off >>= 1) r += __shfl_down(r, off, 64);
    if ((t & 63) == 0) sh[t >> 6] = r;
    __syncthreads();
    if (t == 0) csum[blockIdx.x] = sh[0] + sh[1] + sh[2] + sh[3];
}

// 1 block: chunk scan (16 chunks) then bin scans -> b0, b1, base0
__global__ void k_pick(const int* __restrict__ hist, const int* __restrict__ csum,
                       Ctrl* ctrl, long long i0, long long i1) {
    __shared__ int sh[256];
    __shared__ int c0s, c1s;
    __shared__ long long e0s, e1s;
    int t = threadIdx.x;
    int v = (t < NBINS / 256) ? csum[t] : 0;
    sh[t] = v;
    __syncthreads();
    for (int off = 1; off < 256; off <<= 1) {
        int u = (t >= off) ? sh[t - off] : 0;
        __syncthreads(); sh[t] += u; __syncthreads();
    }
    long long excl = (long long)(sh[t] - v);
    if (t < NBINS / 256) {
        if (i0 >= excl && i0 < excl + v) { c0s = t; e0s = excl; }
        if (i1 >= excl && i1 < excl + v) { c1s = t; e1s = excl; }
    }
    __syncthreads();
    int c0 = c0s, c1 = c1s;
    long long e0 = e0s, e1 = e1s;

    int hv = hist[c0 * 256 + t];
    sh[t] = hv; __syncthreads();
    for (int off = 1; off < 256; off <<= 1) {
        int u = (t >= off) ? sh[t - off] : 0;
        __syncthreads(); sh[t] += u; __syncthreads();
    }
    long long be = e0 + (long long)(sh[t] - hv);
    if (i0 >= be && i0 < be + hv) { ctrl->b0 = c0 * 256 + t; ctrl->base0 = (int)be; }
    __syncthreads();

    hv = hist[c1 * 256 + t];
    sh[t] = hv; __syncthreads();
    for (int off = 1; off < 256; off <<= 1) {
        int u = (t >= off) ? sh[t - off] : 0;
        __syncthreads(); sh[t] += u; __syncthreads();
    }
    be = e1 + (long long)(sh[t] - hv);
    if (i1 >= be && i1 < be + hv) { ctrl->b1 = c1 * 256 + t; }
}

__global__ void k_collect(const float* __restrict__ att, int E,
                          Ctrl* ctrl, float* __restrict__ cand) {
    int b0 = ctrl->b0, b1 = ctrl->b1;
    int i = blockIdx.x * blockDim.x + threadIdx.x;
    int stride = gridDim.x * blockDim.x;
    for (; i < E; i += stride) {
        float v = att[i];
        int b = bin_of(v);
        if (b >= b0 && b <= b1) {
            int idx = atomicAdd(&ctrl->cand_cnt, 1);
            if (idx < CAP) cand[idx] = v;
        }
    }
}

__global__ void k_finalize(Ctrl* ctrl, const float* __restrict__ cand,
                           long long i0, long long i1, double frac) {
    __shared__ float sh[CAP];
    __shared__ float s0s, s1s;
    int n = ctrl->cand_cnt;
    if (n > CAP) n = CAP;
    for (int i = threadIdx.x; i < n; i += blockDim.x) sh[i] = cand[i];
    __syncthreads();
    int r0 = (int)(i0 - (long long)ctrl->base0);
    int r1 = (int)(i1 - (long long)ctrl->base0);
    for (int i = threadIdx.x; i < n; i += blockDim.x) {
        float v = sh[i];
        int rank = 0;
        for (int j = 0; j < n; j++) {
            float u = sh[j];
            rank += (u < v) || (u == v && j < i);
        }
        if (rank == r0) s0s = v;
        if (rank == r1) s1s = v;
    }
    __syncthreads();
    if (threadIdx.x == 0) {
        double a = (double)s0s, b = (double)s1s;
        ctrl->thr = b - (b - a) * (1.0 - frac);   // numpy _lerp, t>=0.5 branch
        ctrl->s0 = s0s; ctrl->s1 = s1s;
    }
}

// ---------- count pass: LDS bucket counters for dst AND src, dense flush ----------
__global__ void k_count(const float* __restrict__ att, const int* __restrict__ src,
                        const int* __restrict__ dst, int E, int NB, int NBG,
                        const Ctrl* __restrict__ ctrl, int* __restrict__ cntAll) {
    __shared__ int lD[NBMAX], lS[NBMAX];
    int t = threadIdx.x;
    for (int b = t; b < NB; b += 256) { lD[b] = 0; lS[b] = 0; }
    __syncthreads();
    double thr = ctrl->thr;
    for (int i = blockIdx.x * 256 + t; i < E; i += GBC * 256) {
        float v = att[i];
        if ((double)v > thr) {
            atomicAdd(&lD[dst[i] >> 6], 1);
            atomicAdd(&lS[src[i] >> 6], 1);
        }
    }
    __syncthreads();
    for (int b = t; b < NB; b += 256) {
        cntAll[blockIdx.x * NB + b]       = lD[b];
        cntAll[NBG + blockIdx.x * NB + b] = lS[b];
    }
}

// scan domain j in [0, 2*NBG): (half, bucket, blk) -> cntAll[half*NBG + blk*NB + bucket]
__device__ __forceinline__ int cnt_at(const int* cntAll, int j, int NB, int NBG) {
    int base = 0, r = j;
    if (j >= NBG) { base = NBG; r = j - NBG; }
    return cntAll[base + (r & (GBC - 1)) * NB + (r >> 7)];
}

__global__ void k_scan1(const int* __restrict__ cntAll, int NB, int NBG, int NK2,
                        int* __restrict__ bsum) {
    __shared__ int sh[8];
    int b = blockIdx.x, t = threadIdx.x;
    int j0 = b * SCAN_CH + t * 8;
    int s = 0;
    for (int u = 0; u < 8; u++) {
        int j = j0 + u;
        if (j < NK2) s += cnt_at(cntAll, j, NB, NBG);
    }
    for (int off = 32; off > 0; off >>= 1) s += __shfl_down(s, off, 64);
    if ((t & 63) == 0) sh[t >> 6] = s;
    __syncthreads();
    if (t == 0) bsum[b] = sh[0] + sh[1] + sh[2] + sh[3];
}

__global__ void k_scan2(const int* __restrict__ bsum, int nb,
                        int* __restrict__ boff, int* __restrict__ off2d, int NK2) {
    __shared__ int sh[256];
    int t = threadIdx.x;
    int v = (t < nb) ? bsum[t] : 0;
    sh[t] = v;
    __syncthreads();
    for (int off = 1; off < 256; off <<= 1) {
        int u = (t >= off) ? sh[t - off] : 0;
        __syncthreads(); sh[t] += u; __syncthreads();
    }
    boff[t] = sh[t] - v;
    if (t == 255) off2d[NK2] = sh[255];
}

__global__ void k_scan3(const int* __restrict__ cntAll, int NB, int NBG, int NK2,
                        const int* __restrict__ boff, int* __restrict__ off2d) {
    __shared__ int sh[256];
    int b = blockIdx.x, t = threadIdx.x;
    int j0 = b * SCAN_CH + t * 8;
    int v[8];
    int ts = 0;
    for (int u = 0; u < 8; u++) {
        int j = j0 + u;
        v[u] = (j < NK2) ? cnt_at(cntAll, j, NB, NBG) : 0;
        ts += v[u];
    }
    sh[t] = ts;
    __syncthreads();
    for (int off = 1; off < 256; off <<= 1) {
        int u = (t >= off) ? sh[t - off] : 0;
        __syncthreads(); sh[t] += u; __syncthreads();
    }
    int excl = boff[b] + sh[t] - ts;
    for (int u = 0; u < 8; u++) {
        int j = j0 + u;
        if (j < NK2) off2d[j] = excl;
        excl += v[u];
    }
}

// ---------- scatter: dst-bucketed (src|dlow, f32 v) + src-bucketed (f16 v | slow) ----------
__global__ void k_scatter(const float* __restrict__ att, const int* __restrict__ src,
                          const int* __restrict__ dst, int E, int NB, int NBG,
                          const Ctrl* __restrict__ ctrl, const int* __restrict__ off2d,
                          uint2* __restrict__ ebufD, unsigned* __restrict__ ebufS) {
    __shared__ int baseD[NBMAX], baseS[NBMAX], fD[NBMAX], fS[NBMAX];
    int t = threadIdx.x;
    int K = off2d[NBG];
    for (int b = t; b < NB; b += 256) {
        baseD[b] = off2d[b * GBC + blockIdx.x];
        baseS[b] = off2d[NBG + b * GBC + blockIdx.x] - K;
        fD[b] = 0; fS[b] = 0;
    }
    __syncthreads();
    double thr = ctrl->thr;
    for (int i = blockIdx.x * 256 + t; i < E; i += GBC * 256) {
        float v = att[i];
        if ((double)v > thr) {
            int s = src[i], d = dst[i];
            int bD = d >> 6, bS = s >> 6;
            int pD = baseD[bD] + atomicAdd(&fD[bD], 1);
            uint2 ev; ev.x = (unsigned)s | ((unsigned)(d & 63) << 16);
            ev.y = __float_as_uint(v);
            ebufD[pD] = ev;
            int pS = baseS[bS] + atomicAdd(&fS[bS], 1);
            unsigned hv = (unsigned)__half_as_ushort(__float2half(v));
            ebufS[pS] = hv | ((unsigned)(s & 63) << 16);
        }
    }
}

// per-src-bucket segment sum -> rsums[N] = 1/(sum+eps); also emit xh = f16(x*rsum)
__global__ void k_sums(const int* __restrict__ off2d, int NBG,
                       const unsigned* __restrict__ ebufS,
                       const float* __restrict__ x,
                       float* __restrict__ rsums, __half* __restrict__ xh, int N) {
    __shared__ float s64[64];
    __shared__ float r64[64];
    int b = blockIdx.x, t = threadIdx.x;
    if (t < 64) s64[t] = 0.f;
    __syncthreads();
    int K = off2d[NBG];
    int lo = off2d[NBG + b * GBC] - K;
    int hi = off2d[NBG + (b + 1) * GBC] - K;
    for (int e = lo + t; e < hi; e += 256) {
        unsigned u = ebufS[e];
        atomicAdd(&s64[(u >> 16) & 63],
                  __half2float(__ushort_as_half((unsigned short)(u & 0xFFFFu))));
    }
    __syncthreads();
    if (t < 64) {
        float r = 1.f / (s64[t] + 1e-16f);
        r64[t] = r;
        int node = b * 64 + t;
        if (node < N) rsums[node] = r;
    }
    __syncthreads();
    int base = b * 64 * DCH;
    for (int i = t; i < 64 * DCH; i += 256) {
        int node = b * 64 + (i >> 6);
        if (node < N) xh[base + i] = __float2half(x[base + i] * r64[i >> 6]);
    }
}

// ---------- per-bucket LDS counting sort: bucketed ebufD -> per-node packed CSR ----------
// csr entry: src (low 16) | f16(raw v) (high 16). No normalization here.
__global__ __launch_bounds__(256) void k_sort(const int* __restrict__ off2d,
                                              const uint2* __restrict__ ebufD,
                                              unsigned* __restrict__ csr,
                                              int* __restrict__ rowp, int N) {
    __shared__ int cnt[64], base[65], fill[64];
    int b = blockIdx.x, t = threadIdx.x;
    if (t < 64) { cnt[t] = 0; fill[t] = 0; }
    __syncthreads();
    int lo = off2d[b * GBC], hi = off2d[(b + 1) * GBC];
    for (int e = lo + t; e < hi; e += 256)
        atomicAdd(&cnt[(ebufD[e].x >> 16) & 63], 1);
    __syncthreads();
    if (t == 0) {
        int s = 0;
        for (int i = 0; i < 64; i++) { base[i] = s; s += cnt[i]; }
        base[64] = s;
    }
    __syncthreads();
    if (t <= 64) {
        int node = b * 64 + t;
        if (node <= N) rowp[node] = lo + base[t];
    }
    for (int e = lo + t; e < hi; e += 256) {
        uint2 ev = ebufD[e];
        int dl = (ev.x >> 16) & 63;
        int pos = lo + base[dl] + atomicAdd(&fill[dl], 1);
        unsigned hb = (unsigned)__half_as_ushort(__float2half(__uint_as_float(ev.y)));
        csr[pos] = (ev.x & 0xFFFFu) | (hb << 16);
    }
}

// ---------- spmv: one wave per dst node, packed CSR, f16 gather table ----------
// pass1: zprev=x;  z1 = x + 0.5(az-x);  hout = f16(z1*rsum)
// pass2: z2 = x + 0.5(az-z1)
// pass3: z3 = x + (az-z2)
// pass4: out = (az + 2*z1 + 4*z2 + z3 - 2x)/6        (za=z1, zb=z2, zprev=z3)
__global__ __launch_bounds__(256) void k_spmv(
    const int* __restrict__ rowp, const unsigned* __restrict__ csr,
    const __half* __restrict__ hin, __half* __restrict__ hout,
    const float* __restrict__ rsums, const float* __restrict__ x,
    const float* __restrict__ zprev, float* __restrict__ zout,
    const float* __restrict__ za, const float* __restrict__ zb,
    int N, int pass)
{
    int node = blockIdx.x * 4 + threadIdx.y;
    if (node >= N) return;
    int lane = threadIdx.x;
    int beg = rowp[node], end = rowp[node + 1];

    float a0 = 0.f, a1 = 0.f, a2 = 0.f, a3 = 0.f;
    float a4 = 0.f, a5 = 0.f, a6 = 0.f, a7 = 0.f;
    for (int e = beg; e < end; e += 64) {
        int m = end - e;
        if (m > 64) m = 64;
        unsigned ev = 0;
        if (lane < m) ev = csr[e + lane];
        int j = 0;
        for (; j + 8 <= m; j += 8) {
            unsigned e0 = (unsigned)__shfl((int)ev, j,     64);
            unsigned e1 = (unsigned)__shfl((int)ev, j + 1, 64);
            unsigned e2 = (unsigned)__shfl((int)ev, j + 2, 64);
            unsigned e3 = (unsigned)__shfl((int)ev, j + 3, 64);
            unsigned e4 = (unsigned)__shfl((int)ev, j + 4, 64);
            unsigned e5 = (unsigned)__shfl((int)ev, j + 5, 64);
            unsigned e6 = (unsigned)__shfl((int)ev, j + 6, 64);
            unsigned e7 = (unsigned)__shfl((int)ev, j + 7, 64);
            float z0 = __half2float(hin[(e0 & 0xFFFFu) * DCH + lane]);
            float z1 = __half2float(hin[(e1 & 0xFFFFu) * DCH + lane]);
            float z2 = __half2float(hin[(e2 & 0xFFFFu) * DCH + lane]);
            float z3 = __half2float(hin[(e3 & 0xFFFFu) * DCH + lane]);
            float z4 = __half2float(hin[(e4 & 0xFFFFu) * DCH + lane]);
            float z5 = __half2float(hin[(e5 & 0xFFFFu) * DCH + lane]);
            float z6 = __half2float(hin[(e6 & 0xFFFFu) * DCH + lane]);
            float z7 = __half2float(hin[(e7 & 0xFFFFu) * DCH + lane]);
            a0 = fmaf(__half2float(__ushort_as_half((unsigned short)(e0 >> 16))), z0, a0);
            a1 = fmaf(__half2float(__ushort_as_half((unsigned short)(e1 >> 16))), z1, a1);
            a2 = fmaf(__half2float(__ushort_as_half((unsigned short)(e2 >> 16))), z2, a2);
            a3 = fmaf(__half2float(__ushort_as_half((unsigned short)(e3 >> 16))), z3, a3);
            a4 = fmaf(__half2float(__ushort_as_half((unsigned short)(e4 >> 16))), z4, a4);
            a5 = fmaf(__half2float(__ushort_as_half((unsigned short)(e5 >> 16))), z5, a5);
            a6 = fmaf(__half2float(__ushort_as_half((unsigned short)(e6 >> 16))), z6, a6);
            a7 = fmaf(__half2float(__ushort_as_half((unsigned short)(e7 >> 16))), z7, a7);
        }
        for (; j < m; j++) {
            unsigned e0 = (unsigned)__shfl((int)ev, j, 64);
            float z0 = __half2float(hin[(e0 & 0xFFFFu) * DCH + lane]);
            a0 = fmaf(__half2float(__ushort_as_half((unsigned short)(e0 >> 16))), z0, a0);
        }
    }
    float az = ((a0 + a1) + (a2 + a3)) + ((a4 + a5) + (a6 + a7));

    int idx = node * DCH + lane;
    float k = az - zprev[idx];
    if (pass <= 2) {
        float zo = x[idx] + 0.5f * k;
        zout[idx] = zo;
        hout[idx] = __float2half(zo * rsums[node]);
    } else if (pass == 3) {
        float zo = x[idx] + k;
        zout[idx] = zo;
        hout[idx] = __float2half(zo * rsums[node]);
    } else {
        zout[idx] = (az + 2.f * za[idx] + 4.f * zb[idx] + zprev[idx] - 2.f * x[idx]) * (1.0f / 6.0f);
    }
}

extern "C" void kernel_launch(void* const* d_in, const int* in_sizes, int n_in,
                              void* d_out, int out_size, void* d_ws, size_t ws_size,
                              hipStream_t stream) {
    const float* x   = (const float*)d_in[0];
    const float* att = (const float*)d_in[1];
    const int*   ei  = (const int*)d_in[2];
    const int E = in_sizes[1];
    const int N = in_sizes[0] / DCH;     // NOTE: src packed in 16 bits -> requires N <= 65536
    const int* src = ei;
    const int* dst = ei + E;

    const int NB  = (N + 63) >> 6;
    const int NBG = NB * GBC;
    const int NK2 = 2 * NBG;
    const int EK = E - (int)((long long)(0.2 * (double)(E - 1))) + 64;

    char* ws = (char*)d_ws;
    size_t off = 0;
    auto alloc = [&](size_t b) { size_t o = off; off += (b + 255) & ~(size_t)255; return o; };
    int*    hist2d = (int*)   (ws + alloc((size_t)GB_HIST * NBINS * 4));
    int*    hist   = (int*)   (ws + alloc((size_t)NBINS * 4));
    int*    csum   = (int*)   (ws + alloc(64 * 4));
    Ctrl*   ctrl   = (Ctrl*)  (ws + alloc(256));
    float*  cand   = (float*) (ws + alloc((size_t)CAP * 4));
    int*    cntAll = (int*)   (ws + alloc((size_t)NK2 * 4));
    int*    off2d  = (int*)   (ws + alloc(((size_t)NK2 + 1) * 4));
    int*    bsum   = (int*)   (ws + alloc(256 * 4));
    int*    boff   = (int*)   (ws + alloc(256 * 4));
    float*  rsums  = (float*) (ws + alloc((size_t)N * 4));
    int*    rowp   = (int*)   (ws + alloc(((size_t)N + 1) * 4));
    uint2*  ebufD  = (uint2*) (ws + alloc((size_t)EK * 8));
    unsigned* csr32= (unsigned*)(ws + alloc((size_t)EK * 4));
    unsigned* ebufS= (unsigned*)(ws + alloc((size_t)EK * 4));
    float*  z1     = (float*) (ws + alloc((size_t)N * DCH * 4));
    float*  z2     = (float*) (ws + alloc((size_t)N * DCH * 4));
    float*  z3     = (float*) (ws + alloc((size_t)N * DCH * 4));
    __half* h0     = (__half*)(ws + alloc((size_t)N * DCH * 2));
    __half* h1     = (__half*)(ws + alloc((size_t)N * DCH * 2));
    float*  out    = (float*)d_out;

    hipMemsetAsync(ctrl, 0, 256, stream);

    // numpy-style quantile index arithmetic (float64)
    double q   = 1.0 - 0.8;
    double pos = q * (double)(E - 1);
    long long i0 = (long long)floor(pos);
    double frac  = pos - (double)i0;
    long long i1 = i0 + 1;
    if (i1 > (long long)E - 1) i1 = (long long)E - 1;

    const int eb = (E + 255) / 256;
    const int nbscan = (NK2 + SCAN_CH - 1) / SCAN_CH;

    k_hist    <<<GB_HIST, 256, 0, stream>>>(att, E, hist2d);
    k_fold    <<<NBINS / 256, 256, 0, stream>>>(hist2d, hist, csum);
    k_pick    <<<1, 256, 0, stream>>>(hist, csum, ctrl, i0, i1);
    k_collect <<<eb, 256, 0, stream>>>(att, E, ctrl, cand);
    k_finalize<<<1, 256, 0, stream>>>(ctrl, cand, i0, i1, frac);
    k_count   <<<GBC, 256, 0, stream>>>(att, src, dst, E, NB, NBG, ctrl, cntAll);
    k_scan1   <<<nbscan, 256, 0, stream>>>(cntAll, NB, NBG, NK2, bsum);
    k_scan2   <<<1, 256, 0, stream>>>(bsum, nbscan, boff, off2d, NK2);
    k_scan3   <<<nbscan, 256, 0, stream>>>(cntAll, NB, NBG, NK2, boff, off2d);
    k_scatter <<<GBC, 256, 0, stream>>>(att, src, dst, E, NB, NBG, ctrl, off2d,
                                        ebufD, ebufS);
    k_sums    <<<NB, 256, 0, stream>>>(off2d, NBG, ebufS, x, rsums, h0, N);
    k_sort    <<<NB, 256, 0, stream>>>(off2d, ebufD, csr32, rowp, N);

    dim3 blk(64, 4);
    int nb = (N + 3) / 4;
    k_spmv<<<nb, blk, 0, stream>>>(rowp, csr32, h0, h1, rsums, x, x,  z1, nullptr, nullptr, N, 1);
    k_spmv<<<nb, blk, 0, stream>>>(rowp, csr32, h1, h0, rsums, x, z1, z2, nullptr, nullptr, N, 2);
    k_spmv<<<nb, blk, 0, stream>>>(rowp, csr32, h0, h1, rsums, x, z2, z3, nullptr, nullptr, N, 3);
    k_spmv<<<nb, blk, 0, stream>>>(rowp, csr32, h1, nullptr, rsums, x, z3, out, z1, z2, N, 4);
}

// Round 8
// 343.090 us; speedup vs baseline: 1.1258x; 1.1258x over previous
//
#include <hip/hip_runtime.h>
#include <hip/hip_fp16.h>
#include <math.h>

#define NBINS   4096
#define GB_HIST 256     // hist blocks (512 threads each)
#define GBC     128     // scatter slabs == scatter grid
#define SUBC    8       // count sub-blocks per slab
#define CAP     2048
#define DCH     64
#define NBMAX   1024    // max buckets (N <= 65536)
#define SCAN_CH 2048

struct Ctrl {
    double thr;
    int cand_cnt;
    int b0, b1;
    int base0;
    float s0, s1;
};

__device__ __forceinline__ int bin_of(float v) {
    int b = (int)(v * (float)NBINS);
    if (b < 0) b = 0;
    if (b >= NBINS) b = NBINS - 1;
    return b;
}

// ---------- LDS histogram, dense (non-atomic) flush. 256 blocks x 512 ----------
__global__ void k_hist(const float* __restrict__ att, int E, int* __restrict__ hist2d) {
    __shared__ int lh[NBINS];   // 16 KB
    int t = threadIdx.x;
    for (int b = t; b < NBINS; b += 512) lh[b] = 0;
    __syncthreads();
    for (int i = blockIdx.x * 512 + t; i < E; i += GB_HIST * 512)
        atomicAdd(&lh[bin_of(att[i])], 1);
    __syncthreads();
    for (int b = t; b < NBINS; b += 512)
        hist2d[blockIdx.x * NBINS + b] = lh[b];
}

// 64 blocks x 256: each block folds 64 bins; 4 threads per bin sum 64 partials each.
// Emits hist[] and per-64-bin-chunk sums csum[64].
__global__ void k_fold(const int* __restrict__ hist2d, int* __restrict__ hist,
                       int* __restrict__ csum) {
    __shared__ int sh[256];
    int t = threadIdx.x;
    int j = blockIdx.x * 64 + (t & 63);
    int p = t >> 6;   // 0..3
    int s = 0;
    for (int q = 0; q < GB_HIST / 4; q++)
        s += hist2d[(p * (GB_HIST / 4) + q) * NBINS + j];
    sh[t] = s;
    __syncthreads();
    if (p == 0) {
        int h = sh[t] + sh[t + 64] + sh[t + 128] + sh[t + 192];
        hist[j] = h;
        int r = h;
        for (int off = 32; off > 0; off >>= 1) r += __shfl_down(r, off, 64);
        if (t == 0) csum[blockIdx.x] = r;
    }
}

// 1 block x 256: scan 64 chunk-sums, then 64 bins in the hit chunks -> b0, b1, base0
__global__ void k_pick(const int* __restrict__ hist, const int* __restrict__ csum,
                       Ctrl* ctrl, long long i0, long long i1) {
    __shared__ int sh[256];
    __shared__ int c0s, c1s;
    __shared__ long long e0s, e1s;
    int t = threadIdx.x;
    int v = (t < 64) ? csum[t] : 0;
    sh[t] = v;
    __syncthreads();
    for (int off = 1; off < 256; off <<= 1) {
        int u = (t >= off) ? sh[t - off] : 0;
        __syncthreads(); sh[t] += u; __syncthreads();
    }
    long long excl = (long long)(sh[t] - v);
    if (t < 64) {
        if (i0 >= excl && i0 < excl + v) { c0s = t; e0s = excl; }
        if (i1 >= excl && i1 < excl + v) { c1s = t; e1s = excl; }
    }
    __syncthreads();
    int c0 = c0s, c1 = c1s;
    long long e0 = e0s, e1 = e1s;

    int hv = (t < 64) ? hist[c0 * 64 + t] : 0;
    sh[t] = hv; __syncthreads();
    for (int off = 1; off < 256; off <<= 1) {
        int u = (t >= off) ? sh[t - off] : 0;
        __syncthreads(); sh[t] += u; __syncthreads();
    }
    long long be = e0 + (long long)(sh[t] - hv);
    if (t < 64 && i0 >= be && i0 < be + hv) { ctrl->b0 = c0 * 64 + t; ctrl->base0 = (int)be; }
    __syncthreads();

    hv = (t < 64) ? hist[c1 * 64 + t] : 0;
    sh[t] = hv; __syncthreads();
    for (int off = 1; off < 256; off <<= 1) {
        int u = (t >= off) ? sh[t - off] : 0;
        __syncthreads(); sh[t] += u; __syncthreads();
    }
    be = e1 + (long long)(sh[t] - hv);
    if (t < 64 && i1 >= be && i1 < be + hv) { ctrl->b1 = c1 * 64 + t; }
}

__global__ void k_collect(const float* __restrict__ att, int E,
                          Ctrl* ctrl, float* __restrict__ cand) {
    int b0 = ctrl->b0, b1 = ctrl->b1;
    int i = blockIdx.x * blockDim.x + threadIdx.x;
    int stride = gridDim.x * blockDim.x;
    for (; i < E; i += stride) {
        float v = att[i];
        int b = bin_of(v);
        if (b >= b0 && b <= b1) {
            int idx = atomicAdd(&ctrl->cand_cnt, 1);
            if (idx < CAP) cand[idx] = v;
        }
    }
}

__global__ void k_finalize(Ctrl* ctrl, const float* __restrict__ cand,
                           long long i0, long long i1, double frac) {
    __shared__ float sh[CAP];
    __shared__ float s0s, s1s;
    int n = ctrl->cand_cnt;
    if (n > CAP) n = CAP;
    for (int i = threadIdx.x; i < n; i += blockDim.x) sh[i] = cand[i];
    __syncthreads();
    int r0 = (int)(i0 - (long long)ctrl->base0);
    int r1 = (int)(i1 - (long long)ctrl->base0);
    for (int i = threadIdx.x; i < n; i += blockDim.x) {
        float v = sh[i];
        int rank = 0;
        for (int j = 0; j < n; j++) {
            float u = sh[j];
            rank += (u < v) || (u == v && j < i);
        }
        if (rank == r0) s0s = v;
        if (rank == r1) s1s = v;
    }
    __syncthreads();
    if (threadIdx.x == 0) {
        double a = (double)s0s, b = (double)s1s;
        ctrl->thr = b - (b - a) * (1.0 - frac);   // numpy _lerp, t>=0.5 branch
        ctrl->s0 = s0s; ctrl->s1 = s1s;
    }
}

// ---------- count: GBC*SUBC blocks x 256; slab k, sub s; dense flush ----------
// slab k = edges with (i>>10) % GBC == k  (1024-edge chunks), matching k_scatter.
__global__ void k_count(const float* __restrict__ att, const int* __restrict__ src,
                        const int* __restrict__ dst, int E, int NB, int NBG,
                        const Ctrl* __restrict__ ctrl, int* __restrict__ cntAll) {
    __shared__ int lD[NBMAX], lS[NBMAX];
    int t = threadIdx.x;
    for (int b = t; b < NB; b += 256) { lD[b] = 0; lS[b] = 0; }
    __syncthreads();
    int bb = blockIdx.x;
    int k = bb & (GBC - 1);
    int s = bb >> 7;            // GBC = 128
    double thr = ctrl->thr;
    for (int c = k + GBC * s; c * 1024 < E; c += GBC * SUBC) {
        int base = c * 1024;
        for (int u = t; u < 1024; u += 256) {
            int i = base + u;
            if (i < E) {
                float v = att[i];
                if ((double)v > thr) {
                    atomicAdd(&lD[dst[i] >> 6], 1);
                    atomicAdd(&lS[src[i] >> 6], 1);
                }
            }
        }
    }
    __syncthreads();
    int dbase = (s * GBC + k) * NB;
    for (int b = t; b < NB; b += 256) {
        cntAll[dbase + b]              = lD[b];
        cntAll[SUBC * NBG + dbase + b] = lS[b];
    }
}

// scan domain j in [0, 2*NBG): (half, bucket=r>>7, blk=r&127); sum SUBC sub-counts
__device__ __forceinline__ int cnt_at(const int* cntAll, int j, int NB, int NBG) {
    int half = (j >= NBG) ? 1 : 0;
    int r = j - half * NBG;
    int b = r >> 7;
    int k = r & (GBC - 1);
    const int* p = cntAll + half * SUBC * NBG + k * NB + b;
    int s = 0;
    #pragma unroll
    for (int q = 0; q < SUBC; q++) s += p[q * GBC * NB];
    return s;
}

__global__ void k_scan1(const int* __restrict__ cntAll, int NB, int NBG, int NK2,
                        int* __restrict__ bsum) {
    __shared__ int sh[8];
    int b = blockIdx.x, t = threadIdx.x;
    int j0 = b * SCAN_CH + t * 8;
    int s = 0;
    for (int u = 0; u < 8; u++) {
        int j = j0 + u;
        if (j < NK2) s += cnt_at(cntAll, j, NB, NBG);
    }
    for (int off = 32; off > 0; off >>= 1) s += __shfl_down(s, off, 64);
    if ((t & 63) == 0) sh[t >> 6] = s;
    __syncthreads();
    if (t == 0) bsum[b] = sh[0] + sh[1] + sh[2] + sh[3];
}

__global__ void k_scan2(const int* __restrict__ bsum, int nb,
                        int* __restrict__ boff, int* __restrict__ off2d, int NK2) {
    __shared__ int sh[256];
    int t = threadIdx.x;
    int v = (t < nb) ? bsum[t] : 0;
    sh[t] = v;
    __syncthreads();
    for (int off = 1; off < 256; off <<= 1) {
        int u = (t >= off) ? sh[t - off] : 0;
        __syncthreads(); sh[t] += u; __syncthreads();
    }
    boff[t] = sh[t] - v;
    if (t == 255) off2d[NK2] = sh[255];
}

__global__ void k_scan3(const int* __restrict__ cntAll, int NB, int NBG, int NK2,
                        const int* __restrict__ boff, int* __restrict__ off2d) {
    __shared__ int sh[256];
    int b = blockIdx.x, t = threadIdx.x;
    int j0 = b * SCAN_CH + t * 8;
    int v[8];
    int ts = 0;
    for (int u = 0; u < 8; u++) {
        int j = j0 + u;
        v[u] = (j < NK2) ? cnt_at(cntAll, j, NB, NBG) : 0;
        ts += v[u];
    }
    sh[t] = ts;
    __syncthreads();
    for (int off = 1; off < 256; off <<= 1) {
        int u = (t >= off) ? sh[t - off] : 0;
        __syncthreads(); sh[t] += u; __syncthreads();
    }
    int excl = boff[b] + sh[t] - ts;
    for (int u = 0; u < 8; u++) {
        int j = j0 + u;
        if (j < NK2) off2d[j] = excl;
        excl += v[u];
    }
}

// ---------- scatter: GBC blocks x 1024 threads; slab = (i>>10) % GBC ----------
__global__ __launch_bounds__(1024) void k_scatter(
    const float* __restrict__ att, const int* __restrict__ src,
    const int* __restrict__ dst, int E, int NB, int NBG,
    const Ctrl* __restrict__ ctrl, const int* __restrict__ off2d,
    uint2* __restrict__ ebufD, unsigned* __restrict__ ebufS) {
    __shared__ int baseD[NBMAX], baseS[NBMAX], fD[NBMAX], fS[NBMAX];
    int t = threadIdx.x;
    int K = off2d[NBG];
    for (int b = t; b < NB; b += 1024) {
        baseD[b] = off2d[b * GBC + blockIdx.x];
        baseS[b] = off2d[NBG + b * GBC + blockIdx.x] - K;
        fD[b] = 0; fS[b] = 0;
    }
    __syncthreads();
    double thr = ctrl->thr;
    for (int i = blockIdx.x * 1024 + t; i < E; i += GBC * 1024) {
        float v = att[i];
        if ((double)v > thr) {
            int s = src[i], d = dst[i];
            int bD = d >> 6, bS = s >> 6;
            int pD = baseD[bD] + atomicAdd(&fD[bD], 1);
            uint2 ev; ev.x = (unsigned)s | ((unsigned)(d & 63) << 16);
            ev.y = __float_as_uint(v);
            ebufD[pD] = ev;
            int pS = baseS[bS] + atomicAdd(&fS[bS], 1);
            unsigned hv = (unsigned)__half_as_ushort(__float2half(v));
            ebufS[pS] = hv | ((unsigned)(s & 63) << 16);
        }
    }
}

// ---------- fused per-bucket: src-segment sums -> rsums; xh = f16(x*rsum);
//            dst-segment counting sort -> packed CSR + rowp ----------
__global__ __launch_bounds__(256) void k_sortsum(
    const int* __restrict__ off2d, int NBG,
    const unsigned* __restrict__ ebufS, const uint2* __restrict__ ebufD,
    const float* __restrict__ x, float* __restrict__ rsums, __half* __restrict__ xh,
    unsigned* __restrict__ csr, int* __restrict__ rowp, int N) {
    __shared__ float s64[64];
    __shared__ float r64[64];
    __shared__ int cnt[64], basea[65], fill[64];
    int b = blockIdx.x, t = threadIdx.x;
    if (t < 64) { s64[t] = 0.f; cnt[t] = 0; fill[t] = 0; }
    __syncthreads();
    int K = off2d[NBG];
    int slo = off2d[NBG + b * GBC] - K;
    int shi = off2d[NBG + (b + 1) * GBC] - K;
    for (int e = slo + t; e < shi; e += 256) {
        unsigned u = ebufS[e];
        atomicAdd(&s64[(u >> 16) & 63],
                  __half2float(__ushort_as_half((unsigned short)(u & 0xFFFFu))));
    }
    int dlo = off2d[b * GBC], dhi = off2d[(b + 1) * GBC];
    for (int e = dlo + t; e < dhi; e += 256)
        atomicAdd(&cnt[(ebufD[e].x >> 16) & 63], 1);
    __syncthreads();
    if (t < 64) {
        float r = 1.f / (s64[t] + 1e-16f);
        r64[t] = r;
        int node = b * 64 + t;
        if (node < N) rsums[node] = r;
    }
    if (t == 0) {
        int s = 0;
        for (int i = 0; i < 64; i++) { basea[i] = s; s += cnt[i]; }
        basea[64] = s;
    }
    __syncthreads();
    if (t <= 64) {
        int node = b * 64 + t;
        if (node <= N) rowp[node] = dlo + basea[t];
    }
    int xbase = b * 64 * DCH;
    for (int i = t; i < 64 * DCH; i += 256) {
        int node = b * 64 + (i >> 6);
        if (node < N) xh[xbase + i] = __float2half(x[xbase + i] * r64[i >> 6]);
    }
    for (int e = dlo + t; e < dhi; e += 256) {
        uint2 ev = ebufD[e];
        int dl = (ev.x >> 16) & 63;
        int pos = dlo + basea[dl] + atomicAdd(&fill[dl], 1);
        unsigned hb = (unsigned)__half_as_ushort(__float2half(__uint_as_float(ev.y)));
        csr[pos] = (ev.x & 0xFFFFu) | (hb << 16);
    }
}

// ---------- spmv: one wave per dst node, packed CSR, f16 gather table ----------
// pass1: zprev=x;  z1 = x + 0.5(az-x);  hout = f16(z1*rsum)
// pass2: z2 = x + 0.5(az-z1)
// pass3: z3 = x + (az-z2)
// pass4: out = (az + 2*z1 + 4*z2 + z3 - 2x)/6        (za=z1, zb=z2, zprev=z3)
__global__ __launch_bounds__(256) void k_spmv(
    const int* __restrict__ rowp, const unsigned* __restrict__ csr,
    const __half* __restrict__ hin, __half* __restrict__ hout,
    const float* __restrict__ rsums, const float* __restrict__ x,
    const float* __restrict__ zprev, float* __restrict__ zout,
    const float* __restrict__ za, const float* __restrict__ zb,
    int N, int pass)
{
    int node = blockIdx.x * 4 + threadIdx.y;
    if (node >= N) return;
    int lane = threadIdx.x;
    int beg = rowp[node], end = rowp[node + 1];

    float a0 = 0.f, a1 = 0.f, a2 = 0.f, a3 = 0.f;
    float a4 = 0.f, a5 = 0.f, a6 = 0.f, a7 = 0.f;
    for (int e = beg; e < end; e += 64) {
        int m = end - e;
        if (m > 64) m = 64;
        unsigned ev = 0;
        if (lane < m) ev = csr[e + lane];
        int j = 0;
        for (; j + 8 <= m; j += 8) {
            unsigned e0 = (unsigned)__shfl((int)ev, j,     64);
            unsigned e1 = (unsigned)__shfl((int)ev, j + 1, 64);
            unsigned e2 = (unsigned)__shfl((int)ev, j + 2, 64);
            unsigned e3 = (unsigned)__shfl((int)ev, j + 3, 64);
            unsigned e4 = (unsigned)__shfl((int)ev, j + 4, 64);
            unsigned e5 = (unsigned)__shfl((int)ev, j + 5, 64);
            unsigned e6 = (unsigned)__shfl((int)ev, j + 6, 64);
            unsigned e7 = (unsigned)__shfl((int)ev, j + 7, 64);
            float z0 = __half2float(hin[(e0 & 0xFFFFu) * DCH + lane]);
            float z1 = __half2float(hin[(e1 & 0xFFFFu) * DCH + lane]);
            float z2 = __half2float(hin[(e2 & 0xFFFFu) * DCH + lane]);
            float z3 = __half2float(hin[(e3 & 0xFFFFu) * DCH + lane]);
            float z4 = __half2float(hin[(e4 & 0xFFFFu) * DCH + lane]);
            float z5 = __half2float(hin[(e5 & 0xFFFFu) * DCH + lane]);
            float z6 = __half2float(hin[(e6 & 0xFFFFu) * DCH + lane]);
            float z7 = __half2float(hin[(e7 & 0xFFFFu) * DCH + lane]);
            a0 = fmaf(__half2float(__ushort_as_half((unsigned short)(e0 >> 16))), z0, a0);
            a1 = fmaf(__half2float(__ushort_as_half((unsigned short)(e1 >> 16))), z1, a1);
            a2 = fmaf(__half2float(__ushort_as_half((unsigned short)(e2 >> 16))), z2, a2);
            a3 = fmaf(__half2float(__ushort_as_half((unsigned short)(e3 >> 16))), z3, a3);
            a4 = fmaf(__half2float(__ushort_as_half((unsigned short)(e4 >> 16))), z4, a4);
            a5 = fmaf(__half2float(__ushort_as_half((unsigned short)(e5 >> 16))), z5, a5);
            a6 = fmaf(__half2float(__ushort_as_half((unsigned short)(e6 >> 16))), z6, a6);
            a7 = fmaf(__half2float(__ushort_as_half((unsigned short)(e7 >> 16))), z7, a7);
        }
        for (; j < m; j++) {
            unsigned e0 = (unsigned)__shfl((int)ev, j, 64);
            float z0 = __half2float(hin[(e0 & 0xFFFFu) * DCH + lane]);
            a0 = fmaf(__half2float(__ushort_as_half((unsigned short)(e0 >> 16))), z0, a0);
        }
    }
    float az = ((a0 + a1) + (a2 + a3)) + ((a4 + a5) + (a6 + a7));

    int idx = node * DCH + lane;
    float k = az - zprev[idx];
    if (pass <= 2) {
        float zo = x[idx] + 0.5f * k;
        zout[idx] = zo;
        hout[idx] = __float2half(zo * rsums[node]);
    } else if (pass == 3) {
        float zo = x[idx] + k;
        zout[idx] = zo;
        hout[idx] = __float2half(zo * rsums[node]);
    } else {
        zout[idx] = (az + 2.f * za[idx] + 4.f * zb[idx] + zprev[idx] - 2.f * x[idx]) * (1.0f / 6.0f);
    }
}

extern "C" void kernel_launch(void* const* d_in, const int* in_sizes, int n_in,
                              void* d_out, int out_size, void* d_ws, size_t ws_size,
                              hipStream_t stream) {
    const float* x   = (const float*)d_in[0];
    const float* att = (const float*)d_in[1];
    const int*   ei  = (const int*)d_in[2];
    const int E = in_sizes[1];
    const int N = in_sizes[0] / DCH;     // NOTE: src packed in 16 bits -> requires N <= 65536
    const int* src = ei;
    const int* dst = ei + E;

    const int NB  = (N + 63) >> 6;
    const int NBG = NB * GBC;
    const int NK2 = 2 * NBG;
    const int EK = E - (int)((long long)(0.2 * (double)(E - 1))) + 64;

    char* ws = (char*)d_ws;
    size_t off = 0;
    auto alloc = [&](size_t b) { size_t o = off; off += (b + 255) & ~(size_t)255; return o; };
    int*    hist2d = (int*)   (ws + alloc((size_t)GB_HIST * NBINS * 4));
    int*    hist   = (int*)   (ws + alloc((size_t)NBINS * 4));
    int*    csum   = (int*)   (ws + alloc(64 * 4));
    Ctrl*   ctrl   = (Ctrl*)  (ws + alloc(256));
    float*  cand   = (float*) (ws + alloc((size_t)CAP * 4));
    int*    cntAll = (int*)   (ws + alloc((size_t)2 * SUBC * NBG * 4));
    int*    off2d  = (int*)   (ws + alloc(((size_t)NK2 + 1) * 4));
    int*    bsum   = (int*)   (ws + alloc(256 * 4));
    int*    boff   = (int*)   (ws + alloc(256 * 4));
    float*  rsums  = (float*) (ws + alloc((size_t)N * 4));
    int*    rowp   = (int*)   (ws + alloc(((size_t)N + 1) * 4));
    uint2*  ebufD  = (uint2*) (ws + alloc((size_t)EK * 8));
    unsigned* csr32= (unsigned*)(ws + alloc((size_t)EK * 4));
    unsigned* ebufS= (unsigned*)(ws + alloc((size_t)EK * 4));
    float*  z1     = (float*) (ws + alloc((size_t)N * DCH * 4));
    float*  z2     = (float*) (ws + alloc((size_t)N * DCH * 4));
    float*  z3     = (float*) (ws + alloc((size_t)N * DCH * 4));
    __half* h0     = (__half*)(ws + alloc((size_t)N * DCH * 2));
    __half* h1     = (__half*)(ws + alloc((size_t)N * DCH * 2));
    float*  out    = (float*)d_out;

    hipMemsetAsync(ctrl, 0, 256, stream);

    // numpy-style quantile index arithmetic (float64)
    double q   = 1.0 - 0.8;
    double pos = q * (double)(E - 1);
    long long i0 = (long long)floor(pos);
    double frac  = pos - (double)i0;
    long long i1 = i0 + 1;
    if (i1 > (long long)E - 1) i1 = (long long)E - 1;

    const int eb = (E + 255) / 256;
    const int nbscan = (NK2 + SCAN_CH - 1) / SCAN_CH;

    k_hist    <<<GB_HIST, 512, 0, stream>>>(att, E, hist2d);
    k_fold    <<<NBINS / 64, 256, 0, stream>>>(hist2d, hist, csum);
    k_pick    <<<1, 256, 0, stream>>>(hist, csum, ctrl, i0, i1);
    k_collect <<<eb, 256, 0, stream>>>(att, E, ctrl, cand);
    k_finalize<<<1, 256, 0, stream>>>(ctrl, cand, i0, i1, frac);
    k_count   <<<GBC * SUBC, 256, 0, stream>>>(att, src, dst, E, NB, NBG, ctrl, cntAll);
    k_scan1   <<<nbscan, 256, 0, stream>>>(cntAll, NB, NBG, NK2, bsum);
    k_scan2   <<<1, 256, 0, stream>>>(bsum, nbscan, boff, off2d, NK2);
    k_scan3   <<<nbscan, 256, 0, stream>>>(cntAll, NB, NBG, NK2, boff, off2d);
    k_scatter <<<GBC, 1024, 0, stream>>>(att, src, dst, E, NB, NBG, ctrl, off2d,
                                         ebufD, ebufS);
    k_sortsum <<<NB, 256, 0, stream>>>(off2d, NBG, ebufS, ebufD, x, rsums, h0,
                                       csr32, rowp, N);

    dim3 blk(64, 4);
    int nb = (N + 3) / 4;
    k_spmv<<<nb, blk, 0, stream>>>(rowp, csr32, h0, h1, rsums, x, x,  z1, nullptr, nullptr, N, 1);
    k_spmv<<<nb, blk, 0, stream>>>(rowp, csr32, h1, h0, rsums, x, z1, z2, nullptr, nullptr, N, 2);
    k_spmv<<<nb, blk, 0, stream>>>(rowp, csr32, h0, h1, rsums, x, z2, z3, nullptr, nullptr, N, 3);
    k_spmv<<<nb, blk, 0, stream>>>(rowp, csr32, h1, nullptr, rsums, x, z3, out, z1, z2, N, 4);
}

// Round 9
// 333.728 us; speedup vs baseline: 1.1574x; 1.0281x over previous
//
#include <hip/hip_runtime.h>
#include <hip/hip_fp16.h>
#include <math.h>

#define NBINS   4096
#define GB_HIST 256     // hist blocks (512 threads each)
#define GBC     256     // scatter slabs == scatter grid
#define SUBC    4       // count sub-blocks per slab
#define CAP     2048
#define DCH     64
#define BKT     128     // nodes per bucket
#define NBMAX   512     // max buckets (N <= 65536)
#define SCAN_CH 2048

struct Ctrl {
    double thr;
    int cand_cnt;
    int b0, b1;
    int base0;
    float s0, s1;
};

__device__ __forceinline__ int bin_of(float v) {
    int b = (int)(v * (float)NBINS);
    if (b < 0) b = 0;
    if (b >= NBINS) b = NBINS - 1;
    return b;
}

// ---------- LDS histogram, dense (non-atomic) flush. 256 blocks x 512 ----------
__global__ void k_hist(const float* __restrict__ att, int E, int* __restrict__ hist2d) {
    __shared__ int lh[NBINS];   // 16 KB
    int t = threadIdx.x;
    for (int b = t; b < NBINS; b += 512) lh[b] = 0;
    __syncthreads();
    for (int i = blockIdx.x * 512 + t; i < E; i += GB_HIST * 512)
        atomicAdd(&lh[bin_of(att[i])], 1);
    __syncthreads();
    for (int b = t; b < NBINS; b += 512)
        hist2d[blockIdx.x * NBINS + b] = lh[b];
}

// 64 blocks x 256: each block folds 64 bins; 4 threads per bin sum 64 partials each.
__global__ void k_fold(const int* __restrict__ hist2d, int* __restrict__ hist,
                       int* __restrict__ csum) {
    __shared__ int sh[256];
    int t = threadIdx.x;
    int j = blockIdx.x * 64 + (t & 63);
    int p = t >> 6;   // 0..3
    int s = 0;
    for (int q = 0; q < GB_HIST / 4; q++)
        s += hist2d[(p * (GB_HIST / 4) + q) * NBINS + j];
    sh[t] = s;
    __syncthreads();
    if (p == 0) {
        int h = sh[t] + sh[t + 64] + sh[t + 128] + sh[t + 192];
        hist[j] = h;
        int r = h;
        for (int off = 32; off > 0; off >>= 1) r += __shfl_down(r, off, 64);
        if (t == 0) csum[blockIdx.x] = r;
    }
}

// 1 block x 256: scan 64 chunk-sums, then 64 bins in the hit chunks -> b0, b1, base0
__global__ void k_pick(const int* __restrict__ hist, const int* __restrict__ csum,
                       Ctrl* ctrl, long long i0, long long i1) {
    __shared__ int sh[256];
    __shared__ int c0s, c1s;
    __shared__ long long e0s, e1s;
    int t = threadIdx.x;
    int v = (t < 64) ? csum[t] : 0;
    sh[t] = v;
    __syncthreads();
    for (int off = 1; off < 256; off <<= 1) {
        int u = (t >= off) ? sh[t - off] : 0;
        __syncthreads(); sh[t] += u; __syncthreads();
    }
    long long excl = (long long)(sh[t] - v);
    if (t < 64) {
        if (i0 >= excl && i0 < excl + v) { c0s = t; e0s = excl; }
        if (i1 >= excl && i1 < excl + v) { c1s = t; e1s = excl; }
    }
    __syncthreads();
    int c0 = c0s, c1 = c1s;
    long long e0 = e0s, e1 = e1s;

    int hv = (t < 64) ? hist[c0 * 64 + t] : 0;
    sh[t] = hv; __syncthreads();
    for (int off = 1; off < 256; off <<= 1) {
        int u = (t >= off) ? sh[t - off] : 0;
        __syncthreads(); sh[t] += u; __syncthreads();
    }
    long long be = e0 + (long long)(sh[t] - hv);
    if (t < 64 && i0 >= be && i0 < be + hv) { ctrl->b0 = c0 * 64 + t; ctrl->base0 = (int)be; }
    __syncthreads();

    hv = (t < 64) ? hist[c1 * 64 + t] : 0;
    sh[t] = hv; __syncthreads();
    for (int off = 1; off < 256; off <<= 1) {
        int u = (t >= off) ? sh[t - off] : 0;
        __syncthreads(); sh[t] += u; __syncthreads();
    }
    be = e1 + (long long)(sh[t] - hv);
    if (t < 64 && i1 >= be && i1 < be + hv) { ctrl->b1 = c1 * 64 + t; }
}

__global__ void k_collect(const float* __restrict__ att, int E,
                          Ctrl* ctrl, float* __restrict__ cand) {
    int b0 = ctrl->b0, b1 = ctrl->b1;
    int i = blockIdx.x * blockDim.x + threadIdx.x;
    int stride = gridDim.x * blockDim.x;
    for (; i < E; i += stride) {
        float v = att[i];
        int b = bin_of(v);
        if (b >= b0 && b <= b1) {
            int idx = atomicAdd(&ctrl->cand_cnt, 1);
            if (idx < CAP) cand[idx] = v;
        }
    }
}

__global__ void k_finalize(Ctrl* ctrl, const float* __restrict__ cand,
                           long long i0, long long i1, double frac) {
    __shared__ float sh[CAP];
    __shared__ float s0s, s1s;
    int n = ctrl->cand_cnt;
    if (n > CAP) n = CAP;
    for (int i = threadIdx.x; i < n; i += blockDim.x) sh[i] = cand[i];
    __syncthreads();
    int r0 = (int)(i0 - (long long)ctrl->base0);
    int r1 = (int)(i1 - (long long)ctrl->base0);
    for (int i = threadIdx.x; i < n; i += blockDim.x) {
        float v = sh[i];
        int rank = 0;
        for (int j = 0; j < n; j++) {
            float u = sh[j];
            rank += (u < v) || (u == v && j < i);
        }
        if (rank == r0) s0s = v;
        if (rank == r1) s1s = v;
    }
    __syncthreads();
    if (threadIdx.x == 0) {
        double a = (double)s0s, b = (double)s1s;
        ctrl->thr = b - (b - a) * (1.0 - frac);   // numpy _lerp, t>=0.5 branch
        ctrl->s0 = s0s; ctrl->s1 = s1s;
    }
}

// ---------- count: GBC*SUBC blocks x 256; slab k, sub s; dense flush ----------
// slab k = edges in 1024-chunks with chunk % GBC == k, matching k_scatter.
__global__ void k_count(const float* __restrict__ att, const int* __restrict__ src,
                        const int* __restrict__ dst, int E, int NB, int NBG,
                        const Ctrl* __restrict__ ctrl, int* __restrict__ cntAll) {
    __shared__ int lD[NBMAX], lS[NBMAX];
    int t = threadIdx.x;
    for (int b = t; b < NB; b += 256) { lD[b] = 0; lS[b] = 0; }
    __syncthreads();
    int bb = blockIdx.x;
    int k = bb & (GBC - 1);
    int s = bb >> 8;            // GBC = 256
    double thr = ctrl->thr;
    for (int c = k + GBC * s; c * 1024 < E; c += GBC * SUBC) {
        int base = c * 1024;
        for (int u = t; u < 1024; u += 256) {
            int i = base + u;
            if (i < E) {
                float v = att[i];
                if ((double)v > thr) {
                    atomicAdd(&lD[dst[i] >> 7], 1);
                    atomicAdd(&lS[src[i] >> 7], 1);
                }
            }
        }
    }
    __syncthreads();
    int dbase = (s * GBC + k) * NB;
    for (int b = t; b < NB; b += 256) {
        cntAll[dbase + b]              = lD[b];
        cntAll[SUBC * NBG + dbase + b] = lS[b];
    }
}

// scan domain j in [0, 2*NBG): (half, bucket=r>>8, blk=r&255); sum SUBC sub-counts
__device__ __forceinline__ int cnt_at(const int* cntAll, int j, int NB, int NBG) {
    int half = (j >= NBG) ? 1 : 0;
    int r = j - half * NBG;
    int b = r >> 8;
    int k = r & (GBC - 1);
    const int* p = cntAll + half * SUBC * NBG + k * NB + b;
    int s = 0;
    #pragma unroll
    for (int q = 0; q < SUBC; q++) s += p[q * GBC * NB];
    return s;
}

__global__ void k_scan1(const int* __restrict__ cntAll, int NB, int NBG, int NK2,
                        int* __restrict__ bsum) {
    __shared__ int sh[8];
    int b = blockIdx.x, t = threadIdx.x;
    int j0 = b * SCAN_CH + t * 8;
    int s = 0;
    for (int u = 0; u < 8; u++) {
        int j = j0 + u;
        if (j < NK2) s += cnt_at(cntAll, j, NB, NBG);
    }
    for (int off = 32; off > 0; off >>= 1) s += __shfl_down(s, off, 64);
    if ((t & 63) == 0) sh[t >> 6] = s;
    __syncthreads();
    if (t == 0) bsum[b] = sh[0] + sh[1] + sh[2] + sh[3];
}

__global__ void k_scan2(const int* __restrict__ bsum, int nb,
                        int* __restrict__ boff, int* __restrict__ off2d, int NK2) {
    __shared__ int sh[256];
    int t = threadIdx.x;
    int v = (t < nb) ? bsum[t] : 0;
    sh[t] = v;
    __syncthreads();
    for (int off = 1; off < 256; off <<= 1) {
        int u = (t >= off) ? sh[t - off] : 0;
        __syncthreads(); sh[t] += u; __syncthreads();
    }
    boff[t] = sh[t] - v;
    if (t == 255) off2d[NK2] = sh[255];
}

__global__ void k_scan3(const int* __restrict__ cntAll, int NB, int NBG, int NK2,
                        const int* __restrict__ boff, int* __restrict__ off2d) {
    __shared__ int sh[256];
    int b = blockIdx.x, t = threadIdx.x;
    int j0 = b * SCAN_CH + t * 8;
    int v[8];
    int ts = 0;
    for (int u = 0; u < 8; u++) {
        int j = j0 + u;
        v[u] = (j < NK2) ? cnt_at(cntAll, j, NB, NBG) : 0;
        ts += v[u];
    }
    sh[t] = ts;
    __syncthreads();
    for (int off = 1; off < 256; off <<= 1) {
        int u = (t >= off) ? sh[t - off] : 0;
        __syncthreads(); sh[t] += u; __syncthreads();
    }
    int excl = boff[b] + sh[t] - ts;
    for (int u = 0; u < 8; u++) {
        int j = j0 + u;
        if (j < NK2) off2d[j] = excl;
        excl += v[u];
    }
}

// ---------- scatter: GBC blocks x 1024 threads ----------
__global__ __launch_bounds__(1024) void k_scatter(
    const float* __restrict__ att, const int* __restrict__ src,
    const int* __restrict__ dst, int E, int NB, int NBG,
    const Ctrl* __restrict__ ctrl, const int* __restrict__ off2d,
    uint2* __restrict__ ebufD, unsigned* __restrict__ ebufS) {
    __shared__ int baseD[NBMAX], baseS[NBMAX], fD[NBMAX], fS[NBMAX];
    int t = threadIdx.x;
    int K = off2d[NBG];
    for (int b = t; b < NB; b += 1024) {
        baseD[b] = off2d[b * GBC + blockIdx.x];
        baseS[b] = off2d[NBG + b * GBC + blockIdx.x] - K;
        fD[b] = 0; fS[b] = 0;
    }
    __syncthreads();
    double thr = ctrl->thr;
    for (int i = blockIdx.x * 1024 + t; i < E; i += GBC * 1024) {
        float v = att[i];
        if ((double)v > thr) {
            int s = src[i], d = dst[i];
            int bD = d >> 7, bS = s >> 7;
            int pD = baseD[bD] + atomicAdd(&fD[bD], 1);
            uint2 ev; ev.x = (unsigned)s | ((unsigned)(d & 127) << 16);
            ev.y = __float_as_uint(v);
            ebufD[pD] = ev;
            int pS = baseS[bS] + atomicAdd(&fS[bS], 1);
            unsigned hv = (unsigned)__half_as_ushort(__float2half(v));
            ebufS[pS] = hv | ((unsigned)(s & 127) << 16);
        }
    }
}

// ---------- fused per-bucket (128 nodes): src-segment sums -> rs, sinv;
//            hx = f16(x*rs); dst-segment counting sort -> packed CSR + rowp ----------
__global__ __launch_bounds__(256) void k_sortsum(
    const int* __restrict__ off2d, int NBG,
    const unsigned* __restrict__ ebufS, const uint2* __restrict__ ebufD,
    const float* __restrict__ x, float* __restrict__ rsums, float* __restrict__ sinv,
    __half* __restrict__ hx,
    unsigned* __restrict__ csr, int* __restrict__ rowp, int N) {
    __shared__ float s128[BKT];
    __shared__ float r128[BKT];
    __shared__ int cnt[BKT], basea[BKT + 1], fill[BKT];
    int b = blockIdx.x, t = threadIdx.x;
    if (t < BKT) { s128[t] = 0.f; cnt[t] = 0; fill[t] = 0; }
    __syncthreads();
    int K = off2d[NBG];
    int slo = off2d[NBG + b * GBC] - K;
    int shi = off2d[NBG + (b + 1) * GBC] - K;
    for (int e = slo + t; e < shi; e += 256) {
        unsigned u = ebufS[e];
        atomicAdd(&s128[(u >> 16) & 127],
                  __half2float(__ushort_as_half((unsigned short)(u & 0xFFFFu))));
    }
    int dlo = off2d[b * GBC], dhi = off2d[(b + 1) * GBC];
    for (int e = dlo + t; e < dhi; e += 256)
        atomicAdd(&cnt[(ebufD[e].x >> 16) & 127], 1);
    __syncthreads();
    if (t < BKT) {
        float sv = (s128[t] > 0.f) ? (s128[t] + 1e-16f) : 1.0f;
        float r = 1.f / sv;
        r128[t] = r;
        int node = b * BKT + t;
        if (node < N) { rsums[node] = r; sinv[node] = sv; }
    }
    if (t == 0) {
        int s = 0;
        for (int i = 0; i < BKT; i++) { basea[i] = s; s += cnt[i]; }
        basea[BKT] = s;
    }
    __syncthreads();
    if (t <= BKT) {
        int node = b * BKT + t;
        if (node <= N) rowp[node] = dlo + basea[t];
    }
    int xbase = b * BKT * DCH;
    for (int i = t; i < BKT * DCH; i += 256) {
        int node = b * BKT + (i >> 6);
        if (node < N) hx[xbase + i] = __float2half(x[xbase + i] * r128[i >> 6]);
    }
    for (int e = dlo + t; e < dhi; e += 256) {
        uint2 ev = ebufD[e];
        int dl = (ev.x >> 16) & 127;
        int pos = dlo + basea[dl] + atomicAdd(&fill[dl], 1);
        unsigned hb = (unsigned)__half_as_ushort(__float2half(__uint_as_float(ev.y)));
        csr[pos] = (ev.x & 0xFFFFu) | (hb << 16);
    }
}

// ---------- spmv: one wave per dst node, packed CSR, f16 state carry ----------
// state recovery: z = h * sinv  (h = f16(z*rs), rs = 1/sinv)
// pass1: hin=hx;  x=hin*si;  z1 = 0.5(az+x);        hout=h1
// pass2: hin=h1;  x=hx*si;   z2 = x + 0.5(az - z1); hout=h2
// pass3: hin=h2;  x=hx*si;   z3 = x + (az - z2);    hout=h3
// pass4: hin=h3;  out = (az + 2*z1 + 4*z2 + z3 - 2x)/6  (z1=ha*si, z2=hb*si, z3=hin*si, x f32)
__global__ __launch_bounds__(256) void k_spmv(
    const int* __restrict__ rowp, const unsigned* __restrict__ csr,
    const __half* __restrict__ hin, __half* __restrict__ hout,
    const __half* __restrict__ hxb, const __half* __restrict__ ha,
    const __half* __restrict__ hb,
    const float* __restrict__ rsums, const float* __restrict__ sinv,
    const float* __restrict__ x, float* __restrict__ zout,
    int N, int pass)
{
    int node = blockIdx.x * 4 + threadIdx.y;
    if (node >= N) return;
    int lane = threadIdx.x;
    int beg = rowp[node], end = rowp[node + 1];

    float a0 = 0.f, a1 = 0.f, a2 = 0.f, a3 = 0.f;
    float a4 = 0.f, a5 = 0.f, a6 = 0.f, a7 = 0.f;
    for (int e = beg; e < end; e += 64) {
        int m = end - e;
        if (m > 64) m = 64;
        unsigned ev = 0;
        if (lane < m) ev = csr[e + lane];
        int j = 0;
        for (; j + 8 <= m; j += 8) {
            unsigned e0 = (unsigned)__shfl((int)ev, j,     64);
            unsigned e1 = (unsigned)__shfl((int)ev, j + 1, 64);
            unsigned e2 = (unsigned)__shfl((int)ev, j + 2, 64);
            unsigned e3 = (unsigned)__shfl((int)ev, j + 3, 64);
            unsigned e4 = (unsigned)__shfl((int)ev, j + 4, 64);
            unsigned e5 = (unsigned)__shfl((int)ev, j + 5, 64);
            unsigned e6 = (unsigned)__shfl((int)ev, j + 6, 64);
            unsigned e7 = (unsigned)__shfl((int)ev, j + 7, 64);
            float z0 = __half2float(hin[(e0 & 0xFFFFu) * DCH + lane]);
            float z1 = __half2float(hin[(e1 & 0xFFFFu) * DCH + lane]);
            float z2 = __half2float(hin[(e2 & 0xFFFFu) * DCH + lane]);
            float z3 = __half2float(hin[(e3 & 0xFFFFu) * DCH + lane]);
            float z4 = __half2float(hin[(e4 & 0xFFFFu) * DCH + lane]);
            float z5 = __half2float(hin[(e5 & 0xFFFFu) * DCH + lane]);
            float z6 = __half2float(hin[(e6 & 0xFFFFu) * DCH + lane]);
            float z7 = __half2float(hin[(e7 & 0xFFFFu) * DCH + lane]);
            a0 = fmaf(__half2float(__ushort_as_half((unsigned short)(e0 >> 16))), z0, a0);
            a1 = fmaf(__half2float(__ushort_as_half((unsigned short)(e1 >> 16))), z1, a1);
            a2 = fmaf(__half2float(__ushort_as_half((unsigned short)(e2 >> 16))), z2, a2);
            a3 = fmaf(__half2float(__ushort_as_half((unsigned short)(e3 >> 16))), z3, a3);
            a4 = fmaf(__half2float(__ushort_as_half((unsigned short)(e4 >> 16))), z4, a4);
            a5 = fmaf(__half2float(__ushort_as_half((unsigned short)(e5 >> 16))), z5, a5);
            a6 = fmaf(__half2float(__ushort_as_half((unsigned short)(e6 >> 16))), z6, a6);
            a7 = fmaf(__half2float(__ushort_as_half((unsigned short)(e7 >> 16))), z7, a7);
        }
        for (; j < m; j++) {
            unsigned e0 = (unsigned)__shfl((int)ev, j, 64);
            float z0 = __half2float(hin[(e0 & 0xFFFFu) * DCH + lane]);
            a0 = fmaf(__half2float(__ushort_as_half((unsigned short)(e0 >> 16))), z0, a0);
        }
    }
    float az = ((a0 + a1) + (a2 + a3)) + ((a4 + a5) + (a6 + a7));

    int idx = node * DCH + lane;
    float si = sinv[node];
    if (pass == 1) {
        float xv = __half2float(hin[idx]) * si;
        float zo = 0.5f * (az + xv);
        hout[idx] = __float2half(zo * rsums[node]);
    } else if (pass == 2) {
        float xv = __half2float(hxb[idx]) * si;
        float z1v = __half2float(hin[idx]) * si;
        float zo = xv + 0.5f * (az - z1v);
        hout[idx] = __float2half(zo * rsums[node]);
    } else if (pass == 3) {
        float xv = __half2float(hxb[idx]) * si;
        float z2v = __half2float(hin[idx]) * si;
        float zo = xv + (az - z2v);
        hout[idx] = __float2half(zo * rsums[node]);
    } else {
        float z1v = __half2float(ha[idx]) * si;
        float z2v = __half2float(hb[idx]) * si;
        float z3v = __half2float(hin[idx]) * si;
        zout[idx] = (az + 2.f * z1v + 4.f * z2v + z3v - 2.f * x[idx]) * (1.0f / 6.0f);
    }
}

extern "C" void kernel_launch(void* const* d_in, const int* in_sizes, int n_in,
                              void* d_out, int out_size, void* d_ws, size_t ws_size,
                              hipStream_t stream) {
    const float* x   = (const float*)d_in[0];
    const float* att = (const float*)d_in[1];
    const int*   ei  = (const int*)d_in[2];
    const int E = in_sizes[1];
    const int N = in_sizes[0] / DCH;     // NOTE: src packed in 16 bits -> requires N <= 65536
    const int* src = ei;
    const int* dst = ei + E;

    const int NB  = (N + BKT - 1) / BKT;   // 391
    const int NBG = NB * GBC;
    const int NK2 = 2 * NBG;
    const int EK = E - (int)((long long)(0.2 * (double)(E - 1))) + 64;

    char* ws = (char*)d_ws;
    size_t off = 0;
    auto alloc = [&](size_t b) { size_t o = off; off += (b + 255) & ~(size_t)255; return o; };
    int*    hist2d = (int*)   (ws + alloc((size_t)GB_HIST * NBINS * 4));
    int*    hist   = (int*)   (ws + alloc((size_t)NBINS * 4));
    int*    csum   = (int*)   (ws + alloc(64 * 4));
    Ctrl*   ctrl   = (Ctrl*)  (ws + alloc(256));
    float*  cand   = (float*) (ws + alloc((size_t)CAP * 4));
    int*    cntAll = (int*)   (ws + alloc((size_t)2 * SUBC * NBG * 4));
    int*    off2d  = (int*)   (ws + alloc(((size_t)NK2 + 1) * 4));
    int*    bsum   = (int*)   (ws + alloc(256 * 4));
    int*    boff   = (int*)   (ws + alloc(256 * 4));
    float*  rsums  = (float*) (ws + alloc((size_t)N * 4));
    float*  sinv   = (float*) (ws + alloc((size_t)N * 4));
    int*    rowp   = (int*)   (ws + alloc(((size_t)N + 1) * 4));
    uint2*  ebufD  = (uint2*) (ws + alloc((size_t)EK * 8));
    unsigned* csr32= (unsigned*)(ws + alloc((size_t)EK * 4));
    unsigned* ebufS= (unsigned*)(ws + alloc((size_t)EK * 4));
    __half* hx     = (__half*)(ws + alloc((size_t)N * DCH * 2));
    __half* h1     = (__half*)(ws + alloc((size_t)N * DCH * 2));
    __half* h2     = (__half*)(ws + alloc((size_t)N * DCH * 2));
    __half* h3     = (__half*)(ws + alloc((size_t)N * DCH * 2));
    float*  out    = (float*)d_out;

    hipMemsetAsync(ctrl, 0, 256, stream);

    // numpy-style quantile index arithmetic (float64)
    double q   = 1.0 - 0.8;
    double pos = q * (double)(E - 1);
    long long i0 = (long long)floor(pos);
    double frac  = pos - (double)i0;
    long long i1 = i0 + 1;
    if (i1 > (long long)E - 1) i1 = (long long)E - 1;

    const int eb = (E + 255) / 256;
    const int nbscan = (NK2 + SCAN_CH - 1) / SCAN_CH;

    k_hist    <<<GB_HIST, 512, 0, stream>>>(att, E, hist2d);
    k_fold    <<<NBINS / 64, 256, 0, stream>>>(hist2d, hist, csum);
    k_pick    <<<1, 256, 0, stream>>>(hist, csum, ctrl, i0, i1);
    k_collect <<<eb, 256, 0, stream>>>(att, E, ctrl, cand);
    k_finalize<<<1, 256, 0, stream>>>(ctrl, cand, i0, i1, frac);
    k_count   <<<GBC * SUBC, 256, 0, stream>>>(att, src, dst, E, NB, NBG, ctrl, cntAll);
    k_scan1   <<<nbscan, 256, 0, stream>>>(cntAll, NB, NBG, NK2, bsum);
    k_scan2   <<<1, 256, 0, stream>>>(bsum, nbscan, boff, off2d, NK2);
    k_scan3   <<<nbscan, 256, 0, stream>>>(cntAll, NB, NBG, NK2, boff, off2d);
    k_scatter <<<GBC, 1024, 0, stream>>>(att, src, dst, E, NB, NBG, ctrl, off2d,
                                         ebufD, ebufS);
    k_sortsum <<<NB, 256, 0, stream>>>(off2d, NBG, ebufS, ebufD, x, rsums, sinv, hx,
                                       csr32, rowp, N);

    dim3 blk(64, 4);
    int nb = (N + 3) / 4;
    k_spmv<<<nb, blk, 0, stream>>>(rowp, csr32, hx, h1, hx, nullptr, nullptr, rsums, sinv, x, nullptr, N, 1);
    k_spmv<<<nb, blk, 0, stream>>>(rowp, csr32, h1, h2, hx, nullptr, nullptr, rsums, sinv, x, nullptr, N, 2);
    k_spmv<<<nb, blk, 0, stream>>>(rowp, csr32, h2, h3, hx, nullptr, nullptr, rsums, sinv, x, nullptr, N, 3);
    k_spmv<<<nb, blk, 0, stream>>>(rowp, csr32, h3, nullptr, hx, h1, h2, rsums, sinv, x, out, N, 4);
}